// Round 4
// baseline (693.709 us; speedup 1.0000x reference)
//
#include <hip/hip_runtime.h>

#define HW 3136
#define NB 8
#define CD 128
// C^-0.5 * log2(e), folded into the Q projection so attn uses exp2 directly
#define QSCALE 0.12751750206f

typedef __attribute__((ext_vector_type(8))) short short8;
typedef __attribute__((ext_vector_type(4))) float floatx4;
typedef __attribute__((ext_vector_type(4))) unsigned short ushort4v;

static __device__ __forceinline__ unsigned short f2b(float f){
  union { float f; unsigned u; } v; v.f = f;
  unsigned r = v.u + 0x7FFFu + ((v.u >> 16) & 1u);
  return (unsigned short)(r >> 16);
}
static __device__ __forceinline__ unsigned short f2b_trunc(float f){
  union { float f; unsigned u; } v; v.f = f;
  return (unsigned short)(v.u >> 16);
}
static __device__ __forceinline__ float b2f(unsigned short h){
  union { unsigned u; float f; } v; v.u = ((unsigned)h) << 16;
  return v.f;
}

// ---------------------------------------------------------------------------
// 1x1 conv projections via MFMA; W staged once, all 8 batches looped with
// double-buffered X^T. grid (49 hw-tiles, 5 jobs).  [unchanged from R3]
// ---------------------------------------------------------------------------
__global__ __launch_bounds__(256,2) void proj_kernel(
    const float* __restrict__ s, const float* __restrict__ t1, const float* __restrict__ t2,
    const float* __restrict__ wq, const float* __restrict__ bq,
    const float* __restrict__ wk, const float* __restrict__ bk,
    const float* __restrict__ wv, const float* __restrict__ bv,
    unsigned short* __restrict__ qkv)
{
  __shared__ __align__(16) unsigned short WL[CD][136];
  __shared__ __align__(16) unsigned short XT[2][64][136];
  const int job = blockIdx.y;
  const float* x; const float* w; const float* bias; float scl; int cmajor; size_t dstoff;
  switch(job){
    case 0: x=s;  w=wq; bias=bq; scl=QSCALE; cmajor=0; dstoff=0; break;
    case 1: x=t1; w=wk; bias=bk; scl=1.f;    cmajor=0; dstoff=1; break;
    case 2: x=t1; w=wv; bias=bv; scl=1.f;    cmajor=1; dstoff=2; break;
    case 3: x=t2; w=wk; bias=bk; scl=1.f;    cmajor=0; dstoff=3; break;
    default:x=t2; w=wv; bias=bv; scl=1.f;    cmajor=1; dstoff=4; break;
  }
  const size_t TS = (size_t)NB*HW*CD;
  const int hw0 = blockIdx.x * 64;
  const int tid = threadIdx.x;

  for (int i = 0; i < 16; i++){
    int flat = tid + i*256;
    int o = flat >> 5, cq = (flat & 31)*4;
    floatx4 wv4 = *(const floatx4*)(w + (size_t)o*CD + cq);
    ushort4v pk;
    for (int j=0;j<4;j++) pk[j] = f2b(wv4[j]);
    *(ushort4v*)&WL[o][cq] = pk;
  }

  const int m = tid & 15, quad = (tid >> 4) & 3, wv_ = tid >> 6;
  float bb[8];
  for (int nt=0;nt<8;nt++) bb[nt] = bias[nt*16 + m];

  {
    const float* xb = x + hw0;
    for (int i = 0; i < 8; i++){
      int flat = (tid + i*256)*4;
      int c = flat >> 6, hh = flat & 63;
      floatx4 xv = *(const floatx4*)(xb + (size_t)c*HW + hh);
      for (int j=0;j<4;j++) XT[0][hh+j][c] = f2b(xv[j]);
    }
  }

  for (int b = 0; b < NB; b++){
    __syncthreads();
    if (b+1 < NB){
      const float* xb = x + (size_t)(b+1)*CD*HW + hw0;
      int buf = (b+1)&1;
      for (int i = 0; i < 8; i++){
        int flat = (tid + i*256)*4;
        int c = flat >> 6, hh = flat & 63;
        floatx4 xv = *(const floatx4*)(xb + (size_t)c*HW + hh);
        for (int j=0;j<4;j++) XT[buf][hh+j][c] = f2b(xv[j]);
      }
    }
    const int cur = b & 1;
    short8 af[4];
    for (int dk=0;dk<4;dk++)
      af[dk] = *(const short8*)&XT[cur][wv_*16 + m][dk*32 + quad*8];

    unsigned short* dstK = qkv + dstoff*TS + ((size_t)b*HW + hw0)*CD;
    unsigned short* dstV = qkv + dstoff*TS + (size_t)b*CD*HW;
    for (int nt=0;nt<8;nt++){
      floatx4 acc = {bb[nt],bb[nt],bb[nt],bb[nt]};
      for (int dk=0;dk<4;dk++){
        short8 bf = *(const short8*)&WL[nt*16 + m][dk*32 + quad*8];
        acc = __builtin_amdgcn_mfma_f32_16x16x32_bf16(af[dk], bf, acc, 0,0,0);
      }
      if (!cmajor){
        for (int r=0;r<4;r++)
          dstK[(size_t)(wv_*16 + quad*4 + r)*CD + nt*16 + m] = f2b(acc[r]*scl);
      } else {
        ushort4v pk;
        for (int r=0;r<4;r++) pk[r] = f2b(acc[r]*scl);
        *(ushort4v*)&dstV[(size_t)(nt*16 + m)*HW + hw0 + wv_*16 + quad*4] = pk;
      }
    }
  }
}

// ---------------------------------------------------------------------------
// Flash attention. 128-thread blocks (2 waves); each wave owns 32 q rows as
// TWO 16-row m-tiles sharing every K/V fragment read (2x LDS reuse vs R2).
// K-tile = 32 keys/iter (98 iters). 16x16x32 MFMA, 4-deep chains only.
// grid (49, 8, 2) = 784 blocks -> same occupancy/balance as R2.
// ---------------------------------------------------------------------------
#define KSTR 132
#define VSTR 36
#define KL_E (32*KSTR)      // 4224 elems
#define VL_E (128*VSTR)     // 4608 elems
#define PL_E (2*32*VSTR)    // 2304 elems

__global__ __launch_bounds__(128,3) void attn_kernel(
    const unsigned short* __restrict__ qkv,
    unsigned short* __restrict__ Og)
{
  __shared__ __align__(16) unsigned short smem[KL_E + VL_E + PL_E]; // 22272 elems
  unsigned short (*Kl)[KSTR] = (unsigned short(*)[KSTR])smem;
  unsigned short (*Vl)[VSTR] = (unsigned short(*)[VSTR])(smem + KL_E);
  unsigned short (*Pl)[VSTR] = (unsigned short(*)[VSTR])(smem + KL_E + VL_E);

  const int qt = blockIdx.x;
  const int b  = blockIdx.y;
  const int t  = blockIdx.z;
  const size_t TS = (size_t)NB*HW*CD;
  const unsigned short* Q = qkv + (size_t)b*HW*CD;
  const unsigned short* K = qkv + TS*(size_t)(1 + 2*t) + (size_t)b*HW*CD;
  const unsigned short* V = qkv + TS*(size_t)(2 + 2*t) + (size_t)b*CD*HW;

  const int tid  = threadIdx.x;
  const int w    = tid >> 6;
  const int lane = tid & 63;
  const int m    = lane & 15;
  const int quad = lane >> 4;
  const int q0w  = qt*64 + w*32;

  // Q fragments for both m-tiles (A-layout: lane&15 = q row, quad = k chunk)
  short8 qf[2][4];
  for (int mt=0;mt<2;mt++){
    const unsigned short* qr = Q + (size_t)(q0w + mt*16 + m)*CD + quad*8;
    for (int dk=0;dk<4;dk++) qf[mt][dk] = *(const short8*)(qr + dk*32);
  }
  floatx4 Oc[2][8];
  for (int mt=0;mt<2;mt++) for (int i=0;i<8;i++) Oc[mt][i] = (floatx4)0.f;
  float lr[2][4] = {{0.f,0.f,0.f,0.f},{0.f,0.f,0.f,0.f}};

  // staging addresses: K tile 32x128, V tile 128x32 (c-major), 128 threads
  const unsigned short* kg = K + (size_t)(tid>>4)*CD + (tid&15)*8;
  const unsigned short* vg = V + (size_t)(tid>>2)*HW + (tid&3)*8;
  unsigned short* klds = &Kl[tid>>4][(tid&15)*8];
  unsigned short* vlds = &Vl[tid>>2][(tid&3)*8];

  short8 kpre[4], vpre[4];
  for (int i=0;i<4;i++) kpre[i] = *(const short8*)(kg + (size_t)i*8*CD);
  for (int i=0;i<4;i++) vpre[i] = *(const short8*)(vg + (size_t)i*32*HW);

  for (int kt = 0; kt < HW/32; kt++){
    __syncthreads();                       // all waves done reading prev tile
    for (int i=0;i<4;i++) *(short8*)(klds + i*8*KSTR)  = kpre[i];
    for (int i=0;i<4;i++) *(short8*)(vlds + i*32*VSTR) = vpre[i];
    __syncthreads();
    if (kt < HW/32 - 1){
      kg += 32*CD; vg += 32;
      for (int i=0;i<4;i++) kpre[i] = *(const short8*)(kg + (size_t)i*8*CD);
      for (int i=0;i<4;i++) vpre[i] = *(const short8*)(vg + (size_t)i*32*HW);
    }

    // scores: each kf read feeds both m-tiles
    floatx4 sc[2][2];
    for (int mt=0;mt<2;mt++) for (int nt=0;nt<2;nt++) sc[mt][nt] = (floatx4)0.f;
    for (int nt=0;nt<2;nt++){
      for (int dk=0;dk<4;dk++){
        short8 kf = *(const short8*)&Kl[nt*16 + m][dk*32 + quad*8];
        sc[0][nt] = __builtin_amdgcn_mfma_f32_16x16x32_bf16(qf[0][dk], kf, sc[0][nt], 0,0,0);
        sc[1][nt] = __builtin_amdgcn_mfma_f32_16x16x32_bf16(qf[1][dk], kf, sc[1][nt], 0,0,0);
      }
    }
    // p = 2^score, accumulate row-sum partials, pack P to per-wave LDS
    for (int mt=0;mt<2;mt++)
      for (int nt=0;nt<2;nt++)
        for (int r=0;r<4;r++){
          float p = __builtin_amdgcn_exp2f(sc[mt][nt][r]);
          lr[mt][r] += p;
          Pl[w*32 + mt*16 + quad*4 + r][nt*16 + m] = f2b_trunc(p);
        }
    // same-wave P visibility (each wave reads only its own P rows)
    __asm__ volatile("s_waitcnt lgkmcnt(0)" ::: "memory");
    // PV: each vf read feeds both m-tiles; pf covers full K=32 in one read
    short8 pf0 = *(const short8*)&Pl[w*32 +  0 + m][quad*8];
    short8 pf1 = *(const short8*)&Pl[w*32 + 16 + m][quad*8];
    for (int ct=0;ct<8;ct++){
      short8 vf = *(const short8*)&Vl[ct*16 + m][quad*8];
      Oc[0][ct] = __builtin_amdgcn_mfma_f32_16x16x32_bf16(pf0, vf, Oc[0][ct], 0,0,0);
      Oc[1][ct] = __builtin_amdgcn_mfma_f32_16x16x32_bf16(pf1, vf, Oc[1][ct], 0,0,0);
    }
  }

  // row-sum reduction across the 16 lanes of each quad
  for (int mt=0;mt<2;mt++)
    for (int r=0;r<4;r++){
      for (int off=1; off<16; off<<=1)
        lr[mt][r] += __shfl_xor(lr[mt][r], off, 64);
      lr[mt][r] = 1.f / lr[mt][r];
    }

  __syncthreads();                         // done with K/V LDS; reuse as staging
  unsigned short* stg = smem + w*(32*KSTR);   // 32x132 bf16 per wave
  for (int mt=0;mt<2;mt++)
    for (int ct=0;ct<8;ct++)
      for (int r=0;r<4;r++)
        stg[(mt*16 + quad*4 + r)*KSTR + ct*16 + m] = f2b(Oc[mt][ct][r]*lr[mt][r]);
  __asm__ volatile("s_waitcnt lgkmcnt(0)" ::: "memory");
  unsigned short* ob = Og + ((size_t)t*NB + b)*HW*CD + (size_t)q0w*CD;
  for (int i=0;i<8;i++){
    int row = i*4 + (lane>>4);
    ushort4v v4a = *(const ushort4v*)&stg[row*KSTR + (lane&15)*8];
    ushort4v v4b = *(const ushort4v*)&stg[row*KSTR + (lane&15)*8 + 4];
    *(ushort4v*)&ob[(size_t)row*CD + (lane&15)*8]     = v4a;
    *(ushort4v*)&ob[(size_t)row*CD + (lane&15)*8 + 4] = v4b;
  }
}

// ---------------------------------------------------------------------------
// out[b,c,hw] = s[b,c,hw] + 0.5*(O1[b,hw,c] + O2[b,hw,c])
// ---------------------------------------------------------------------------
__global__ __launch_bounds__(256) void combine_kernel(
    const float* __restrict__ s, const unsigned short* __restrict__ Og,
    float* __restrict__ out)
{
  __shared__ float T[32][129];
  const int b   = blockIdx.y;
  const int hw0 = blockIdx.x * 32;
  const int tid = threadIdx.x;
  const unsigned short* O1 = Og + ((size_t)b*HW + hw0)*CD;
  const unsigned short* O2 = O1 + (size_t)NB*HW*CD;
  for (int i=0;i<2;i++){
    int flat = (tid + i*256)*8;
    int row = flat >> 7, col = flat & 127;
    short8 a  = *(const short8*)(O1 + (size_t)row*CD + col);
    short8 c2 = *(const short8*)(O2 + (size_t)row*CD + col);
    for (int j=0;j<8;j++)
      T[row][col+j] = 0.5f*(b2f((unsigned short)a[j]) + b2f((unsigned short)c2[j]));
  }
  __syncthreads();
  const int c  = tid >> 1;
  const int h0 = (tid & 1)*16;
  const float* sr = s   + ((size_t)b*CD + c)*HW + hw0 + h0;
  float*     orow = out + ((size_t)b*CD + c)*HW + hw0 + h0;
  for (int j0=0;j0<16;j0+=4){
    floatx4 sv = *(const floatx4*)(sr + j0);
    floatx4 ov;
    for (int jj=0;jj<4;jj++) ov[jj] = sv[jj] + T[h0+j0+jj][c];
    *(floatx4*)(orow + j0) = ov;
  }
}

extern "C" void kernel_launch(void* const* d_in, const int* in_sizes, int n_in,
                              void* d_out, int out_size, void* d_ws, size_t ws_size,
                              hipStream_t stream)
{
  const float* s  = (const float*)d_in[0];
  const float* t1 = (const float*)d_in[1];
  const float* t2 = (const float*)d_in[2];
  const float* wq = (const float*)d_in[3];
  const float* bq = (const float*)d_in[4];
  const float* wk = (const float*)d_in[5];
  const float* bk = (const float*)d_in[6];
  const float* wv = (const float*)d_in[7];
  const float* bv = (const float*)d_in[8];
  float* out = (float*)d_out;

  unsigned short* qkv = (unsigned short*)d_ws;
  unsigned short* Og  = qkv + (size_t)5*NB*HW*CD;

  hipLaunchKernelGGL(proj_kernel,    dim3(49,5),   dim3(256), 0, stream,
                     s,t1,t2,wq,bq,wk,bk,wv,bv,qkv);
  hipLaunchKernelGGL(attn_kernel,    dim3(49,8,2), dim3(128), 0, stream, qkv, Og);
  hipLaunchKernelGGL(combine_kernel, dim3(98,8),   dim3(256), 0, stream, s, Og, out);
}

// Round 5
// 627.143 us; speedup vs baseline: 1.1061x; 1.1061x over previous
//
#include <hip/hip_runtime.h>

#define HW 3136
#define NB 8
#define CD 128
// C^-0.5 * log2(e), folded into the Q projection so attn uses exp2 directly
#define QSCALE 0.12751750206f

typedef __attribute__((ext_vector_type(8))) short short8;
typedef __attribute__((ext_vector_type(4))) float floatx4;
typedef __attribute__((ext_vector_type(4))) unsigned short ushort4v;

static __device__ __forceinline__ unsigned short f2b(float f){
  union { float f; unsigned u; } v; v.f = f;
  unsigned r = v.u + 0x7FFFu + ((v.u >> 16) & 1u);
  return (unsigned short)(r >> 16);
}
static __device__ __forceinline__ unsigned short f2b_trunc(float f){
  union { float f; unsigned u; } v; v.f = f;
  return (unsigned short)(v.u >> 16);
}
static __device__ __forceinline__ float b2f(unsigned short h){
  union { unsigned u; float f; } v; v.u = ((unsigned)h) << 16;
  return v.f;
}

// ---------------------------------------------------------------------------
// 1x1 conv projections via MFMA. A-fragments loaded directly from global
// (no LDS transpose -> no 16-way staging conflicts). W staged once per block,
// stride 132 (conflict-free b128 frag reads). grid (49 hw, 4 batch-pairs, 5 jobs).
// ---------------------------------------------------------------------------
__global__ __launch_bounds__(256) void proj_kernel(
    const float* __restrict__ s, const float* __restrict__ t1, const float* __restrict__ t2,
    const float* __restrict__ wq, const float* __restrict__ bq,
    const float* __restrict__ wk, const float* __restrict__ bk,
    const float* __restrict__ wv, const float* __restrict__ bv,
    unsigned short* __restrict__ qkv)
{
  __shared__ __align__(16) unsigned short WL[CD][132];   // 33792 B
  const int job = blockIdx.z;
  const float* x; const float* w; const float* bias; float scl; int cmajor; size_t dstoff;
  switch(job){
    case 0: x=s;  w=wq; bias=bq; scl=QSCALE; cmajor=0; dstoff=0; break;
    case 1: x=t1; w=wk; bias=bk; scl=1.f;    cmajor=0; dstoff=1; break;
    case 2: x=t1; w=wv; bias=bv; scl=1.f;    cmajor=1; dstoff=2; break;
    case 3: x=t2; w=wk; bias=bk; scl=1.f;    cmajor=0; dstoff=3; break;
    default:x=t2; w=wv; bias=bv; scl=1.f;    cmajor=1; dstoff=4; break;
  }
  const size_t TS = (size_t)NB*HW*CD;
  const int hw0 = blockIdx.x * 64;
  const int tid = threadIdx.x;

  for (int i = 0; i < 16; i++){
    int flat = tid + i*256;
    int o = flat >> 5, cq = (flat & 31)*4;
    floatx4 wv4 = *(const floatx4*)(w + (size_t)o*CD + cq);
    ushort4v pk;
    for (int j=0;j<4;j++) pk[j] = f2b(wv4[j]);
    *(ushort4v*)&WL[o][cq] = pk;
  }
  __syncthreads();

  const int m = tid & 15, quad = (tid >> 4) & 3, wv_ = tid >> 6;
  float bb[8];
  for (int nt=0;nt<8;nt++) bb[nt] = bias[nt*16 + m];

  for (int bb2 = 0; bb2 < 2; bb2++){
    const int b = blockIdx.y*2 + bb2;
    const float* xb = x + (size_t)b*CD*HW + hw0 + wv_*16 + m;
    // A-fragments straight from global: lanes m = consecutive hw (coalesced)
    short8 af[4];
    for (int dk=0;dk<4;dk++){
      for (int j=0;j<8;j++){
        int c = dk*32 + quad*8 + j;
        af[dk][j] = (short)f2b(xb[(size_t)c*HW]);
      }
    }
    unsigned short* dstK = qkv + dstoff*TS + ((size_t)b*HW + hw0)*CD;
    unsigned short* dstV = qkv + dstoff*TS + (size_t)b*CD*HW;
    for (int nt=0;nt<8;nt++){
      floatx4 acc = {bb[nt],bb[nt],bb[nt],bb[nt]};
      for (int dk=0;dk<4;dk++){
        short8 bf = *(const short8*)&WL[nt*16 + m][dk*32 + quad*8];
        acc = __builtin_amdgcn_mfma_f32_16x16x32_bf16(af[dk], bf, acc, 0,0,0);
      }
      if (!cmajor){
        for (int r=0;r<4;r++)
          dstK[(size_t)(wv_*16 + quad*4 + r)*CD + nt*16 + m] = f2b(acc[r]*scl);
      } else {
        ushort4v pk;
        for (int r=0;r<4;r++) pk[r] = f2b(acc[r]*scl);
        *(ushort4v*)&dstV[(size_t)(nt*16 + m)*HW + hw0 + wv_*16 + quad*4] = pk;
      }
    }
  }
}

// ---------------------------------------------------------------------------
// Flash attention: R2 skeleton (256-thread blocks, K-tile 64, 49 iters,
// 2 barriers) + dual 16-row m-tiles per wave (every K/V frag read feeds 2
// MFMAs) + conflict-free strides + XCD-grouped 1D grid (400 blocks).
// ---------------------------------------------------------------------------
#define KSTR 132
#define VSTR 68
#define PSTR 68
#define KL_E (64*KSTR)      // 8448 shorts
#define VL_E (128*VSTR)     // 8704
#define PL_E (4*32*PSTR)    // 8704

__global__ __launch_bounds__(256,3) void attn_kernel(
    const unsigned short* __restrict__ qkv,
    unsigned short* __restrict__ Og)
{
  __shared__ __align__(16) unsigned short smem[KL_E + VL_E + PL_E]; // 51712 B
  unsigned short (*Kl)[KSTR] = (unsigned short(*)[KSTR])smem;
  unsigned short (*Vl)[VSTR] = (unsigned short(*)[VSTR])(smem + KL_E);
  unsigned short (*Pl)[PSTR] = (unsigned short(*)[PSTR])(smem + KL_E + VL_E);

  // XCD grouping: all 25 blocks of one (b,t) share lin mod 16 -> same XCD
  const int lin = blockIdx.x;
  const int qt  = lin >> 4;          // 0..24
  const int g   = lin & 15;
  const int b   = g >> 1;
  const int t   = g & 1;
  const size_t TS = (size_t)NB*HW*CD;
  const unsigned short* Q = qkv + (size_t)b*HW*CD;
  const unsigned short* K = qkv + TS*(size_t)(1 + 2*t) + (size_t)b*HW*CD;
  const unsigned short* V = qkv + TS*(size_t)(2 + 2*t) + (size_t)b*CD*HW;

  const int tid  = threadIdx.x;
  const int w    = tid >> 6;
  const int lane = tid & 63;
  const int m    = lane & 15;
  const int quad = lane >> 4;
  const int q0w  = qt*128 + w*32;    // wave's 32 q rows (2 m-tiles)

  // Q fragments for both m-tiles (A-layout)
  short8 qf[2][4];
  for (int mt=0;mt<2;mt++){
    int qrow = q0w + mt*16 + m; if (qrow >= HW) qrow = HW-1;
    const unsigned short* qr = Q + (size_t)qrow*CD + quad*8;
    for (int dk=0;dk<4;dk++) qf[mt][dk] = *(const short8*)(qr + dk*32);
  }
  floatx4 Oc[2][8];
  for (int mt=0;mt<2;mt++) for (int i=0;i<8;i++) Oc[mt][i] = (floatx4)0.f;
  float lr[2][4] = {{0.f,0.f,0.f,0.f},{0.f,0.f,0.f,0.f}};

  // staging: K tile 64x128 (4 rows/thread), V tile 128x64 c-major (4 rows/thread)
  const unsigned short* kg = K + (size_t)(tid>>4)*CD + (tid&15)*8;
  const unsigned short* vg = V + (size_t)(tid>>3)*HW + (tid&7)*8;
  unsigned short* klds = &Kl[tid>>4][(tid&15)*8];
  unsigned short* vlds = &Vl[tid>>3][(tid&7)*8];

  short8 kpre[4], vpre[4];
  for (int i=0;i<4;i++) kpre[i] = *(const short8*)(kg + (size_t)i*16*CD);
  for (int i=0;i<4;i++) vpre[i] = *(const short8*)(vg + (size_t)i*32*HW);

  for (int kt = 0; kt < HW/64; kt++){
    __syncthreads();                       // all waves done reading prev tile
    for (int i=0;i<4;i++) *(short8*)(klds + i*16*KSTR) = kpre[i];
    for (int i=0;i<4;i++) *(short8*)(vlds + i*32*VSTR) = vpre[i];
    __syncthreads();
    if (kt < HW/64 - 1){
      kg += 64*CD; vg += 64;
      for (int i=0;i<4;i++) kpre[i] = *(const short8*)(kg + (size_t)i*16*CD);
      for (int i=0;i<4;i++) vpre[i] = *(const short8*)(vg + (size_t)i*32*HW);
    }

    // scores per nt-tile: each kf read feeds both m-tiles; sc regs recycled
    for (int nt=0;nt<4;nt++){
      floatx4 s0 = (floatx4)0.f, s1 = (floatx4)0.f;
      for (int dk=0;dk<4;dk++){
        short8 kf = *(const short8*)&Kl[nt*16 + m][dk*32 + quad*8];
        s0 = __builtin_amdgcn_mfma_f32_16x16x32_bf16(qf[0][dk], kf, s0, 0,0,0);
        s1 = __builtin_amdgcn_mfma_f32_16x16x32_bf16(qf[1][dk], kf, s1, 0,0,0);
      }
      for (int r=0;r<4;r++){
        float p0 = __builtin_amdgcn_exp2f(s0[r]);
        float p1 = __builtin_amdgcn_exp2f(s1[r]);
        lr[0][r] += p0;
        lr[1][r] += p1;
        Pl[w*32      + quad*4 + r][nt*16 + m] = f2b_trunc(p0);
        Pl[w*32 + 16 + quad*4 + r][nt*16 + m] = f2b_trunc(p1);
      }
    }
    // same-wave P visibility (each wave reads only its own P rows)
    __asm__ volatile("s_waitcnt lgkmcnt(0)" ::: "memory");
    short8 pf[2][2];
    for (int mt=0;mt<2;mt++)
      for (int kk=0;kk<2;kk++)
        pf[mt][kk] = *(const short8*)&Pl[w*32 + mt*16 + m][kk*32 + quad*8];
    // PV: each vf read feeds both m-tiles
    for (int ct=0;ct<8;ct++){
      short8 vf0 = *(const short8*)&Vl[ct*16 + m][quad*8];
      short8 vf1 = *(const short8*)&Vl[ct*16 + m][32 + quad*8];
      Oc[0][ct] = __builtin_amdgcn_mfma_f32_16x16x32_bf16(pf[0][0], vf0, Oc[0][ct], 0,0,0);
      Oc[0][ct] = __builtin_amdgcn_mfma_f32_16x16x32_bf16(pf[0][1], vf1, Oc[0][ct], 0,0,0);
      Oc[1][ct] = __builtin_amdgcn_mfma_f32_16x16x32_bf16(pf[1][0], vf0, Oc[1][ct], 0,0,0);
      Oc[1][ct] = __builtin_amdgcn_mfma_f32_16x16x32_bf16(pf[1][1], vf1, Oc[1][ct], 0,0,0);
    }
  }

  // row-sum reduction across the 16 lanes of each quad
  for (int mt=0;mt<2;mt++)
    for (int r=0;r<4;r++){
      for (int off=1; off<16; off<<=1)
        lr[mt][r] += __shfl_xor(lr[mt][r], off, 64);
      lr[mt][r] = 1.f / lr[mt][r];
    }

  __syncthreads();                         // done with K/V/P LDS; reuse as staging
  unsigned short* stg = smem + w*(32*KSTR);   // 32x132 bf16 per wave
  for (int mt=0;mt<2;mt++)
    for (int ct=0;ct<8;ct++)
      for (int r=0;r<4;r++)
        stg[(mt*16 + quad*4 + r)*KSTR + ct*16 + m] = f2b(Oc[mt][ct][r]*lr[mt][r]);
  __asm__ volatile("s_waitcnt lgkmcnt(0)" ::: "memory");   // per-wave region
  if (q0w < HW){
    unsigned short* ob = Og + ((size_t)t*NB + b)*HW*CD + (size_t)q0w*CD;
    for (int i=0;i<8;i++){
      int row = i*4 + quad;
      short8 v8 = *(const short8*)&stg[row*KSTR + m*8];
      *(short8*)&ob[(size_t)row*CD + m*8] = v8;
    }
  }
}

// ---------------------------------------------------------------------------
// out[b,c,hw] = s[b,c,hw] + 0.5*(O1[b,hw,c] + O2[b,hw,c])
// ---------------------------------------------------------------------------
__global__ __launch_bounds__(256) void combine_kernel(
    const float* __restrict__ s, const unsigned short* __restrict__ Og,
    float* __restrict__ out)
{
  __shared__ float T[32][129];
  const int b   = blockIdx.y;
  const int hw0 = blockIdx.x * 32;
  const int tid = threadIdx.x;
  const unsigned short* O1 = Og + ((size_t)b*HW + hw0)*CD;
  const unsigned short* O2 = O1 + (size_t)NB*HW*CD;
  for (int i=0;i<2;i++){
    int flat = (tid + i*256)*8;
    int row = flat >> 7, col = flat & 127;
    short8 a  = *(const short8*)(O1 + (size_t)row*CD + col);
    short8 c2 = *(const short8*)(O2 + (size_t)row*CD + col);
    for (int j=0;j<8;j++)
      T[row][col+j] = 0.5f*(b2f((unsigned short)a[j]) + b2f((unsigned short)c2[j]));
  }
  __syncthreads();
  const int c  = tid >> 1;
  const int h0 = (tid & 1)*16;
  const float* sr = s   + ((size_t)b*CD + c)*HW + hw0 + h0;
  float*     orow = out + ((size_t)b*CD + c)*HW + hw0 + h0;
  for (int j0=0;j0<16;j0+=4){
    floatx4 sv = *(const floatx4*)(sr + j0);
    floatx4 ov;
    for (int jj=0;jj<4;jj++) ov[jj] = sv[jj] + T[h0+j0+jj][c];
    *(floatx4*)(orow + j0) = ov;
  }
}

extern "C" void kernel_launch(void* const* d_in, const int* in_sizes, int n_in,
                              void* d_out, int out_size, void* d_ws, size_t ws_size,
                              hipStream_t stream)
{
  const float* s  = (const float*)d_in[0];
  const float* t1 = (const float*)d_in[1];
  const float* t2 = (const float*)d_in[2];
  const float* wq = (const float*)d_in[3];
  const float* bq = (const float*)d_in[4];
  const float* wk = (const float*)d_in[5];
  const float* bk = (const float*)d_in[6];
  const float* wv = (const float*)d_in[7];
  const float* bv = (const float*)d_in[8];
  float* out = (float*)d_out;

  unsigned short* qkv = (unsigned short*)d_ws;
  unsigned short* Og  = qkv + (size_t)5*NB*HW*CD;

  hipLaunchKernelGGL(proj_kernel,    dim3(49,4,5), dim3(256), 0, stream,
                     s,t1,t2,wq,bq,wk,bk,wv,bv,qkv);
  hipLaunchKernelGGL(attn_kernel,    dim3(400),    dim3(256), 0, stream, qkv, Og);
  hipLaunchKernelGGL(combine_kernel, dim3(98,8),   dim3(256), 0, stream, s, Og, out);
}